// Round 3
// baseline (143.385 us; speedup 1.0000x reference)
//
#include <hip/hip_runtime.h>

#define H_IMG 128
#define W_IMG 48
#define CIN   64
#define DM    32
#define NH    8
#define DH    4
#define NPIX  (H_IMG * W_IMG)      // 6144
#define NQ    (NH * 2 * 3072)      // 49152 (head, halfband, query)

// 0.5 (dh^-0.5) * log2(e): fold exp->exp2 conversion into q
#define Q_SCALE 0.7213475204444817f

// raw v_exp_f32 — safe here: |args| bounded by ~30, no denorm concerns
__device__ __forceinline__ float fexp2(float x) { return __builtin_amdgcn_exp2f(x); }

// ---------------------------------------------------------------------------
// Kernel 1: fused QKV 3x3 SAME conv. grid = 3(m) * 8(cg) * 24(pixgrp),
// block=256. Each thread: one pixel, 4 output channels (= one head's dims).
// Output layout: [head][y][x][4] floats (q pre-scaled by Q_SCALE).
// ---------------------------------------------------------------------------
__global__ __launch_bounds__(256) void qkv_conv_kernel(
    const float* __restrict__ x,
    const float* __restrict__ wq, const float* __restrict__ bq,
    const float* __restrict__ wk, const float* __restrict__ bk,
    const float* __restrict__ wv, const float* __restrict__ bv,
    float* __restrict__ qout, float* __restrict__ kout, float* __restrict__ vout)
{
    const int m   = blockIdx.x / 192;                // 0=q 1=k 2=v (uniform)
    const int cg  = (blockIdx.x % 192) / 24;         // head (uniform)
    const int pix = (blockIdx.x % 24) * 256 + threadIdx.x;
    const int y   = pix / W_IMG;
    const int x0  = pix % W_IMG;

    const float* w = (m == 0) ? wq : (m == 1) ? wk : wv;
    const float* b = (m == 0) ? bq : (m == 1) ? bk : bv;

    float acc[4];
    #pragma unroll
    for (int j = 0; j < 4; ++j) acc[j] = b[cg * 4 + j];

    for (int dy = -1; dy <= 1; ++dy) {
        const int yy = y + dy;
        if (yy < 0 || yy >= H_IMG) continue;
        for (int dx = -1; dx <= 1; ++dx) {
            const int xc = x0 + dx;
            if (xc < 0 || xc >= W_IMG) continue;
            const float* xp = x + (yy * W_IMG + xc) * CIN;
            const float* wp = w + ((dy + 1) * 3 + (dx + 1)) * CIN * DM + cg * 4;
            for (int ci = 0; ci < CIN; ci += 4) {
                const float4 xv = *reinterpret_cast<const float4*>(xp + ci);
                #pragma unroll
                for (int j = 0; j < 4; ++j) {
                    acc[j] += xv.x * wp[(ci + 0) * DM + j];
                    acc[j] += xv.y * wp[(ci + 1) * DM + j];
                    acc[j] += xv.z * wp[(ci + 2) * DM + j];
                    acc[j] += xv.w * wp[(ci + 3) * DM + j];
                }
            }
        }
    }

    float* outp  = (m == 0) ? qout : (m == 1) ? kout : vout;
    const float s = (m == 0) ? Q_SCALE : 1.0f;

    *reinterpret_cast<float4*>(outp + ((cg * H_IMG + y) * W_IMG + x0) * 4) =
        make_float4(acc[0] * s, acc[1] * s, acc[2] * s, acc[3] * s);
}

// ---------------------------------------------------------------------------
// Kernel 2a: local attention, split-K partials.
// grid = 8h * 2g * 12qt * S(seg); block=256, thread = one query.
// Segment handles key rows seg*(128/S) .. +(128/S), cols c0..c0+31 (c0=g*16).
// Partials (sum of exp, sum of exp*v) combine by addition across segments.
// K/V addresses are wave-uniform -> scalar loads; q lives in 4 VGPRs.
// ---------------------------------------------------------------------------
__global__ __launch_bounds__(256) void attn_partial_kernel(
    const float* __restrict__ q,
    const float* __restrict__ k,
    const float* __restrict__ v,
    float4* __restrict__ partA,     // [S][NQ]
    float*  __restrict__ partS,     // [S][NQ]
    int S)
{
    const int seg  = blockIdx.x % S;
    const int rest = blockIdx.x / S;
    const int qt   = rest % 12;
    const int g    = (rest / 12) % 2;
    const int h    = rest / 24;

    const int qid = qt * 256 + threadIdx.x;   // 0..3071
    const int qy  = qid / 24;
    const int qx  = g * 24 + (qid % 24);

    const float4 qv = *reinterpret_cast<const float4*>(
        q + ((h * H_IMG + qy) * W_IMG + qx) * 4);

    const int c0 = g * 16;
    const int rows = H_IMG / S;
    const int r0 = seg * rows;
    const float* kb = k + (h * H_IMG * W_IMG) * 4;
    const float* vb = v + (h * H_IMG * W_IMG) * 4;

    float a0 = 0.f, a1 = 0.f, a2 = 0.f, a3 = 0.f, ssum = 0.f;

    for (int r = r0; r < r0 + rows; ++r) {
        const float* kr = kb + (r * W_IMG + c0) * 4;
        const float* vr = vb + (r * W_IMG + c0) * 4;
        #pragma unroll 8
        for (int j = 0; j < 32; ++j) {
            const float4 kk = *reinterpret_cast<const float4*>(kr + j * 4);
            const float4 vv = *reinterpret_cast<const float4*>(vr + j * 4);
            const float dot = qv.x * kk.x + qv.y * kk.y + qv.z * kk.z + qv.w * kk.w;
            const float e = fexp2(dot);      // q pre-scaled by 0.5*log2e
            ssum += e;
            a0 += e * vv.x; a1 += e * vv.y; a2 += e * vv.z; a3 += e * vv.w;
        }
    }

    const int idx = ((h * 2 + g) * 3072 + qid);   // 0..NQ-1
    partA[seg * NQ + idx] = make_float4(a0, a1, a2, a3);
    partS[seg * NQ + idx] = ssum;
}

// ---------------------------------------------------------------------------
// Kernel 2b: combine split-K partials, normalize, write att[y][x][32]
// (channel order h*4+d, conv-ready).
// ---------------------------------------------------------------------------
__global__ __launch_bounds__(256) void attn_reduce_kernel(
    const float4* __restrict__ partA,
    const float*  __restrict__ partS,
    float* __restrict__ att,
    int S)
{
    const int idx = blockIdx.x * 256 + threadIdx.x;   // 0..NQ-1
    const int h   = idx / 6144;
    const int rem = idx % 6144;
    const int g   = rem / 3072;
    const int qid = rem % 3072;
    const int qy  = qid / 24;
    const int qx  = g * 24 + (qid % 24);

    float a0 = 0.f, a1 = 0.f, a2 = 0.f, a3 = 0.f, ssum = 0.f;
    for (int s = 0; s < S; ++s) {
        const float4 pa = partA[s * NQ + idx];
        a0 += pa.x; a1 += pa.y; a2 += pa.z; a3 += pa.w;
        ssum += partS[s * NQ + idx];
    }
    const float inv = 1.0f / ssum;
    *reinterpret_cast<float4*>(att + (qy * W_IMG + qx) * DM + h * 4) =
        make_float4(a0 * inv, a1 * inv, a2 * inv, a3 * inv);
}

// ---------------------------------------------------------------------------
// Kernel 3: output 3x3 SAME conv (32 -> 64 ch, no bias).
// grid = 16(cg) * 24(pixgrp), block=256; thread = pixel, 4 out channels.
// ---------------------------------------------------------------------------
__global__ __launch_bounds__(256) void out_conv_kernel(
    const float* __restrict__ att,
    const float* __restrict__ wo,
    float* __restrict__ out)
{
    const int cg  = blockIdx.x / 24;                 // uniform, 0..15
    const int pix = (blockIdx.x % 24) * 256 + threadIdx.x;
    const int y   = pix / W_IMG;
    const int x0  = pix % W_IMG;

    float acc[4];
    #pragma unroll
    for (int j = 0; j < 4; ++j) acc[j] = 0.f;

    for (int dy = -1; dy <= 1; ++dy) {
        const int yy = y + dy;
        if (yy < 0 || yy >= H_IMG) continue;
        for (int dx = -1; dx <= 1; ++dx) {
            const int xc = x0 + dx;
            if (xc < 0 || xc >= W_IMG) continue;
            const float* ap = att + (yy * W_IMG + xc) * DM;
            const float* wp = wo + ((dy + 1) * 3 + (dx + 1)) * DM * 64 + cg * 4;
            for (int ci = 0; ci < DM; ci += 4) {
                const float4 xv = *reinterpret_cast<const float4*>(ap + ci);
                #pragma unroll
                for (int j = 0; j < 4; ++j) {
                    acc[j] += xv.x * wp[(ci + 0) * 64 + j];
                    acc[j] += xv.y * wp[(ci + 1) * 64 + j];
                    acc[j] += xv.z * wp[(ci + 2) * 64 + j];
                    acc[j] += xv.w * wp[(ci + 3) * 64 + j];
                }
            }
        }
    }

    *reinterpret_cast<float4*>(out + (y * W_IMG + x0) * 64 + cg * 4) =
        make_float4(acc[0], acc[1], acc[2], acc[3]);
}

// ---------------------------------------------------------------------------
extern "C" void kernel_launch(void* const* d_in, const int* in_sizes, int n_in,
                              void* d_out, int out_size, void* d_ws, size_t ws_size,
                              hipStream_t stream)
{
    const float* x  = (const float*)d_in[0];
    const float* wq = (const float*)d_in[1];
    const float* bq = (const float*)d_in[2];
    const float* wk = (const float*)d_in[3];
    const float* bk = (const float*)d_in[4];
    const float* wv = (const float*)d_in[5];
    const float* bv = (const float*)d_in[6];
    const float* wo = (const float*)d_in[7];
    float* out = (float*)d_out;

    // workspace layout (floats): kbuf, vbuf, qbuf(=abuf after attn), partA, partS
    const size_t QKV = (size_t)NH * H_IMG * W_IMG * DH;  // 196608
    float* kbuf = (float*)d_ws;
    float* vbuf = kbuf + QKV;
    float* qbuf = vbuf + QKV;        // reused as att buffer by the reduce
    float* part = qbuf + QKV;

    // pick largest split S in {8,4,2,1} that fits ws
    int S = 8;
    while (S > 1) {
        size_t need = (3 * QKV + (size_t)S * NQ * 5) * sizeof(float);
        if (need <= ws_size) break;
        S >>= 1;
    }
    float4* partA = (float4*)part;                 // S*NQ float4
    float*  partS = part + (size_t)S * NQ * 4;     // S*NQ floats
    float*  abuf  = qbuf;                          // alias (q dead after attn)

    hipLaunchKernelGGL(qkv_conv_kernel, dim3(576), dim3(256), 0, stream,
                       x, wq, bq, wk, bk, wv, bv, qbuf, kbuf, vbuf);

    hipLaunchKernelGGL(attn_partial_kernel, dim3(192 * S), dim3(256), 0, stream,
                       qbuf, kbuf, vbuf, partA, partS, S);

    hipLaunchKernelGGL(attn_reduce_kernel, dim3(NQ / 256), dim3(256), 0, stream,
                       partA, partS, abuf, S);

    hipLaunchKernelGGL(out_conv_kernel, dim3(384), dim3(256), 0, stream,
                       abuf, wo, out);
}

// Round 4
// 135.981 us; speedup vs baseline: 1.0544x; 1.0544x over previous
//
#include <hip/hip_runtime.h>

#define H_IMG 128
#define W_IMG 48
#define CIN   64
#define DM    32
#define NH    8
#define NPIX  6144
#define SSEG  4

// 0.5 (dh^-0.5) * log2(e): fold exp->exp2 conversion into q at conv time
#define Q_SCALE 0.7213475204444817f

typedef _Float16 half4 __attribute__((ext_vector_type(4)));
typedef float    f32x4 __attribute__((ext_vector_type(4)));

__device__ __forceinline__ float fexp2(float x) { return __builtin_amdgcn_exp2f(x); }

// ---------------------------------------------------------------------------
// Kernel 1: fused QKV 3x3 SAME conv (R2-proven config: 3m x 4cg x 24, 256thr,
// 8 ch = 2 heads per thread).  Emits f16 hi/lo q,k (half4 per head-pixel) and
// dim-major f16 V^T planes.  Thread(0,0) also writes the const page
// (8 halfs: 4 zeros, 4 ones) used for dead-lane loads in the attn kernel.
// ---------------------------------------------------------------------------
__global__ __launch_bounds__(256) void qkv_conv_kernel(
    const float* __restrict__ x,
    const float* __restrict__ wq, const float* __restrict__ bq,
    const float* __restrict__ wk, const float* __restrict__ bk,
    const float* __restrict__ wv, const float* __restrict__ bv,
    half4* __restrict__ qhi, half4* __restrict__ qlo,
    half4* __restrict__ khi, half4* __restrict__ klo,
    _Float16* __restrict__ vT, _Float16* __restrict__ page)
{
    const int m   = blockIdx.x / 96;                 // 0=q 1=k 2=v (uniform)
    const int cg  = (blockIdx.x % 96) / 24;          // channel group (uniform)
    const int pix = (blockIdx.x % 24) * 256 + threadIdx.x;
    const int y   = pix / W_IMG;
    const int x0  = pix % W_IMG;

    if (blockIdx.x == 0 && threadIdx.x == 0) {
        #pragma unroll
        for (int i = 0; i < 4; ++i) page[i] = (_Float16)0.0f;
        #pragma unroll
        for (int i = 4; i < 8; ++i) page[i] = (_Float16)1.0f;
    }

    const float* w = (m == 0) ? wq : (m == 1) ? wk : wv;
    const float* b = (m == 0) ? bq : (m == 1) ? bk : bv;

    float acc[8];
    #pragma unroll
    for (int j = 0; j < 8; ++j) acc[j] = b[cg * 8 + j];

    for (int dy = -1; dy <= 1; ++dy) {
        const int yy = y + dy;
        if (yy < 0 || yy >= H_IMG) continue;
        for (int dx = -1; dx <= 1; ++dx) {
            const int xc = x0 + dx;
            if (xc < 0 || xc >= W_IMG) continue;
            const float* xp = x + (yy * W_IMG + xc) * CIN;
            const float* wp = w + ((dy + 1) * 3 + (dx + 1)) * CIN * DM + cg * 8;
            for (int ci = 0; ci < CIN; ci += 4) {
                const float4 xv = *reinterpret_cast<const float4*>(xp + ci);
                #pragma unroll
                for (int j = 0; j < 8; ++j) {
                    acc[j] += xv.x * wp[(ci + 0) * DM + j];
                    acc[j] += xv.y * wp[(ci + 1) * DM + j];
                    acc[j] += xv.z * wp[(ci + 2) * DM + j];
                    acc[j] += xv.w * wp[(ci + 3) * DM + j];
                }
            }
        }
    }

    const float s = (m == 0) ? Q_SCALE : 1.0f;

    #pragma unroll
    for (int hh = 0; hh < 2; ++hh) {
        const int h = cg * 2 + hh;
        float a0 = acc[hh*4+0]*s, a1 = acc[hh*4+1]*s,
              a2 = acc[hh*4+2]*s, a3 = acc[hh*4+3]*s;
        if (m == 2) {
            vT[(h*4+0)*NPIX + pix] = (_Float16)a0;
            vT[(h*4+1)*NPIX + pix] = (_Float16)a1;
            vT[(h*4+2)*NPIX + pix] = (_Float16)a2;
            vT[(h*4+3)*NPIX + pix] = (_Float16)a3;
        } else {
            half4 hi = { (_Float16)a0, (_Float16)a1, (_Float16)a2, (_Float16)a3 };
            half4 lo = { (_Float16)(a0 - (float)hi[0]),
                         (_Float16)(a1 - (float)hi[1]),
                         (_Float16)(a2 - (float)hi[2]),
                         (_Float16)(a3 - (float)hi[3]) };
            half4* dhi = (m == 0) ? qhi : khi;
            half4* dlo = (m == 0) ? qlo : klo;
            dhi[h*NPIX + pix] = hi;
            dlo[h*NPIX + pix] = lo;
        }
    }
}

// ---------------------------------------------------------------------------
// Kernel 2a: MFMA local attention (split-K partials).
// grid = 16(hg) x 192(qt) blocks of 4 waves; wave = (hg, qt, seg).
// Per 16-key tile: S^T = Kh*Qh + Kh*Ql + Kl*Qh via mfma_f32_16x16x16_f16
// (d=4 zero-padded to K=16).  exp2 on the 4 C values -> f16 P fragment,
// which IS the A fragment of the PV mfma (swapped-operand trick).
// V B-fragment: cols 0..3 = V dims (from dim-major vT), col 4 = ones
// (gives ssum), cols 5..15 = zeros.  Dead lanes read a const page via
// zero-multiplied offsets (no branches in the loop).
// ---------------------------------------------------------------------------
__global__ __launch_bounds__(256) void attn_mfma_kernel(
    const half4* __restrict__ qhi, const half4* __restrict__ qlo,
    const half4* __restrict__ khi, const half4* __restrict__ klo,
    const half4* __restrict__ vT4, const half4* __restrict__ page4,
    float* __restrict__ partA,     // [SSEG][16hg][3072 q][4]
    float* __restrict__ partS)     // [SSEG][16hg][3072 q]
{
    const int qt  = blockIdx.x % 192;
    const int hg  = blockIdx.x / 192;
    const int h   = hg >> 1, g = hg & 1;
    const int seg = threadIdx.x >> 6;          // wave id = key segment
    const int lane = threadIdx.x & 63;
    const int c   = lane & 15;                 // col / key-within-tile / query-within-tile
    const int g16 = lane >> 4;                 // k-element group
    const int c0  = g * 16;                    // band start col

    // Q fragment (B operand): lanes g16==0 hold the 4 dims of query qt*16+c
    half4 qh = (half4)(_Float16)0.0f, ql = (half4)(_Float16)0.0f;
    if (g16 == 0) {
        const int q   = qt * 16 + c;
        const int qy  = q / 24;
        const int pix = qy * W_IMG + g * 24 + (q - qy * 24);
        qh = qhi[h * NPIX + pix];
        ql = qlo[h * NPIX + pix];
    }

    // K fragment bases (A operand): lanes g16==0 load key pixel (kr, kcb+c)
    const int km = (g16 == 0) ? 1 : 0;
    const half4* kbh = (g16 == 0) ? (khi + h * NPIX + c) : page4;
    const half4* kbl = (g16 == 0) ? (klo + h * NPIX + c) : page4;

    // V fragment base (B operand): col c<4 -> vT dim plane, c==4 -> ones, else zeros
    const half4* vb; int vm;
    if (c < 4)       { vb = vT4 + (h * 4 + c) * (NPIX / 4) + g16; vm = 1; }
    else if (c == 4) { vb = page4 + 1; vm = 0; }
    else             { vb = page4;     vm = 0; }

    f32x4 o = {0.f, 0.f, 0.f, 0.f};

    #pragma unroll 2
    for (int i = 0; i < 64; ++i) {
        const int kt   = seg * 64 + i;         // key tile (16 keys = half band row)
        const int kr   = kt >> 1;              // key image row
        const int kcb  = c0 + ((kt & 1) << 4); // key col base
        const int koff = kr * W_IMG + kcb;

        const half4 kh = kbh[koff * km];
        const half4 kl = kbl[koff * km];
        const half4 vh = vb[(kr * 12 + (kcb >> 2)) * vm];

        f32x4 st = {0.f, 0.f, 0.f, 0.f};
        st = __builtin_amdgcn_mfma_f32_16x16x16f16(kh, qh, st, 0, 0, 0);
        st = __builtin_amdgcn_mfma_f32_16x16x16f16(kh, ql, st, 0, 0, 0);
        st = __builtin_amdgcn_mfma_f32_16x16x16f16(kl, qh, st, 0, 0, 0);

        half4 p;
        p[0] = (_Float16)fexp2(st[0]);
        p[1] = (_Float16)fexp2(st[1]);
        p[2] = (_Float16)fexp2(st[2]);
        p[3] = (_Float16)fexp2(st[3]);

        o = __builtin_amdgcn_mfma_f32_16x16x16f16(p, vh, o, 0, 0, 0);
    }

    // O fragment: lane holds O[q = qt*16 + 4*g16 + r][col c]; col 4 = ssum
    const int qb = (seg * 16 + hg) * 3072 + qt * 16 + g16 * 4;
    if (c < 4) {
        #pragma unroll
        for (int r = 0; r < 4; ++r) partA[(qb + r) * 4 + c] = o[r];
    } else if (c == 4) {
        #pragma unroll
        for (int r = 0; r < 4; ++r) partS[qb + r] = o[r];
    }
}

// ---------------------------------------------------------------------------
// Kernel 2b: combine split-K partials, normalize, write att[y][x][32].
// ---------------------------------------------------------------------------
__global__ __launch_bounds__(256) void attn_reduce_kernel(
    const f32x4* __restrict__ partA4,
    const float* __restrict__ partS,
    float* __restrict__ att)
{
    const int idx = blockIdx.x * 256 + threadIdx.x;  // 0..49151
    const int hg  = idx / 3072;
    const int q   = idx % 3072;
    const int h   = hg >> 1, g = hg & 1;

    f32x4 a = {0.f, 0.f, 0.f, 0.f};
    float ss = 0.f;
    #pragma unroll
    for (int s = 0; s < SSEG; ++s) {
        a  += partA4[(s * 16 + hg) * 3072 + q];
        ss += partS [(s * 16 + hg) * 3072 + q];
    }
    const float inv = 1.0f / ss;
    const int qy = q / 24;
    const int pix = qy * W_IMG + g * 24 + (q - qy * 24);
    *reinterpret_cast<float4*>(att + pix * DM + h * 4) =
        make_float4(a[0] * inv, a[1] * inv, a[2] * inv, a[3] * inv);
}

// ---------------------------------------------------------------------------
// Kernel 3: output 3x3 SAME conv (32 -> 64 ch, no bias).  R2-proven config.
// ---------------------------------------------------------------------------
__global__ __launch_bounds__(256) void out_conv_kernel(
    const float* __restrict__ att,
    const float* __restrict__ wo,
    float* __restrict__ out)
{
    const int cg  = blockIdx.x / 24;                 // uniform, 0..7
    const int pix = (blockIdx.x % 24) * 256 + threadIdx.x;
    const int y   = pix / W_IMG;
    const int x0  = pix % W_IMG;

    float acc[8];
    #pragma unroll
    for (int j = 0; j < 8; ++j) acc[j] = 0.f;

    for (int dy = -1; dy <= 1; ++dy) {
        const int yy = y + dy;
        if (yy < 0 || yy >= H_IMG) continue;
        for (int dx = -1; dx <= 1; ++dx) {
            const int xc = x0 + dx;
            if (xc < 0 || xc >= W_IMG) continue;
            const float* ap = att + (yy * W_IMG + xc) * DM;
            const float* wp = wo + ((dy + 1) * 3 + (dx + 1)) * DM * 64 + cg * 8;
            for (int ci = 0; ci < DM; ci += 4) {
                const float4 xv = *reinterpret_cast<const float4*>(ap + ci);
                #pragma unroll
                for (int j = 0; j < 8; ++j) {
                    acc[j] += xv.x * wp[(ci + 0) * 64 + j];
                    acc[j] += xv.y * wp[(ci + 1) * 64 + j];
                    acc[j] += xv.z * wp[(ci + 2) * 64 + j];
                    acc[j] += xv.w * wp[(ci + 3) * 64 + j];
                }
            }
        }
    }

    float* op = out + (y * W_IMG + x0) * 64 + cg * 8;
    *reinterpret_cast<float4*>(op + 0) = make_float4(acc[0], acc[1], acc[2], acc[3]);
    *reinterpret_cast<float4*>(op + 4) = make_float4(acc[4], acc[5], acc[6], acc[7]);
}

// ---------------------------------------------------------------------------
extern "C" void kernel_launch(void* const* d_in, const int* in_sizes, int n_in,
                              void* d_out, int out_size, void* d_ws, size_t ws_size,
                              hipStream_t stream)
{
    const float* x  = (const float*)d_in[0];
    const float* wq = (const float*)d_in[1];
    const float* bq = (const float*)d_in[2];
    const float* wk = (const float*)d_in[3];
    const float* bk = (const float*)d_in[4];
    const float* wv = (const float*)d_in[5];
    const float* bv = (const float*)d_in[6];
    const float* wo = (const float*)d_in[7];
    float* out = (float*)d_out;

    // workspace layout (bytes), all offsets 16B-aligned
    char* base = (char*)d_ws;
    half4*    qhi  = (half4*)(base + 0);          //  393216 B (49152 half4)
    half4*    qlo  = (half4*)(base + 393216);
    half4*    khi  = (half4*)(base + 786432);
    half4*    klo  = (half4*)(base + 1179648);
    _Float16* vT   = (_Float16*)(base + 1572864); //  393216 B (196608 half)
    _Float16* page = (_Float16*)(base + 1966080); //     256 B
    float*    partA = (float*)(base + 1966336);   // 3145728 B
    float*    partS = (float*)(base + 5112064);   //  786432 B
    float*    att   = (float*)(base + 5898496);   //  786432 B

    hipLaunchKernelGGL(qkv_conv_kernel, dim3(288), dim3(256), 0, stream,
                       x, wq, bq, wk, bk, wv, bv, qhi, qlo, khi, klo, vT, page);

    hipLaunchKernelGGL(attn_mfma_kernel, dim3(16 * 192), dim3(256), 0, stream,
                       qhi, qlo, khi, klo, (const half4*)vT, (const half4*)page,
                       partA, partS);

    hipLaunchKernelGGL(attn_reduce_kernel, dim3(192), dim3(256), 0, stream,
                       (const f32x4*)partA, partS, att);

    hipLaunchKernelGGL(out_conv_kernel, dim3(192), dim3(256), 0, stream,
                       att, wo, out);
}

// Round 6
// 135.961 us; speedup vs baseline: 1.0546x; 1.0001x over previous
//
#include <hip/hip_runtime.h>

#define H_IMG 128
#define W_IMG 48
#define CIN   64
#define DM    32
#define NH    8
#define NPIX  6144
#define SSEG  2

// 0.5 (dh^-0.5) * log2(e): fold exp->exp2 conversion into q at conv time
#define Q_SCALE 0.7213475204444817f

typedef _Float16 half4 __attribute__((ext_vector_type(4)));
typedef __fp16   fp16x2 __attribute__((ext_vector_type(2)));
typedef float    f32x4 __attribute__((ext_vector_type(4)));

__device__ __forceinline__ float fexp2(float x) { return __builtin_amdgcn_exp2f(x); }

// exp2 the 4 logits of an S^T fragment and pack to f16 (RTZ; consistent in
// numerator and denominator so the bias cancels in the softmax ratio)
__device__ __forceinline__ half4 exp_pack(f32x4 s) {
    fp16x2 lo = __builtin_amdgcn_cvt_pkrtz(fexp2(s[0]), fexp2(s[1]));
    fp16x2 hi = __builtin_amdgcn_cvt_pkrtz(fexp2(s[2]), fexp2(s[3]));
    half4 p;
    p[0] = (_Float16)lo[0]; p[1] = (_Float16)lo[1];
    p[2] = (_Float16)hi[0]; p[3] = (_Float16)hi[1];
    return p;
}

// ---------------------------------------------------------------------------
// Kernel 1: fused QKV 3x3 SAME conv (3m x 4cg x 24, 256 thr, 2 heads/thread).
// Emits f16 hi/lo q,k (half4 per head-pixel) and 5-plane dim-major f16 V:
// vT[h*5 + d][pix] for d=0..3, plane d=4 = all ones (softmax denominator
// column for the PV mfma).
// ---------------------------------------------------------------------------
__global__ __launch_bounds__(256) void qkv_conv_kernel(
    const float* __restrict__ x,
    const float* __restrict__ wq, const float* __restrict__ bq,
    const float* __restrict__ wk, const float* __restrict__ bk,
    const float* __restrict__ wv, const float* __restrict__ bv,
    half4* __restrict__ qhi, half4* __restrict__ qlo,
    half4* __restrict__ khi, half4* __restrict__ klo,
    _Float16* __restrict__ vT)
{
    const int m   = blockIdx.x / 96;                 // 0=q 1=k 2=v (uniform)
    const int cg  = (blockIdx.x % 96) / 24;          // channel group (uniform)
    const int pix = (blockIdx.x % 24) * 256 + threadIdx.x;
    const int y   = pix / W_IMG;
    const int x0  = pix % W_IMG;

    const float* w = (m == 0) ? wq : (m == 1) ? wk : wv;
    const float* b = (m == 0) ? bq : (m == 1) ? bk : bv;

    float acc[8];
    #pragma unroll
    for (int j = 0; j < 8; ++j) acc[j] = b[cg * 8 + j];

    for (int dy = -1; dy <= 1; ++dy) {
        const int yy = y + dy;
        if (yy < 0 || yy >= H_IMG) continue;
        for (int dx = -1; dx <= 1; ++dx) {
            const int xc = x0 + dx;
            if (xc < 0 || xc >= W_IMG) continue;
            const float* xp = x + (yy * W_IMG + xc) * CIN;
            const float* wp = w + ((dy + 1) * 3 + (dx + 1)) * CIN * DM + cg * 8;
            for (int ci = 0; ci < CIN; ci += 4) {
                const float4 xv = *reinterpret_cast<const float4*>(xp + ci);
                #pragma unroll
                for (int j = 0; j < 8; ++j) {
                    acc[j] += xv.x * wp[(ci + 0) * DM + j];
                    acc[j] += xv.y * wp[(ci + 1) * DM + j];
                    acc[j] += xv.z * wp[(ci + 2) * DM + j];
                    acc[j] += xv.w * wp[(ci + 3) * DM + j];
                }
            }
        }
    }

    const float s = (m == 0) ? Q_SCALE : 1.0f;

    #pragma unroll
    for (int hh = 0; hh < 2; ++hh) {
        const int h = cg * 2 + hh;
        float a0 = acc[hh*4+0]*s, a1 = acc[hh*4+1]*s,
              a2 = acc[hh*4+2]*s, a3 = acc[hh*4+3]*s;
        if (m == 2) {
            vT[(h*5+0)*NPIX + pix] = (_Float16)a0;
            vT[(h*5+1)*NPIX + pix] = (_Float16)a1;
            vT[(h*5+2)*NPIX + pix] = (_Float16)a2;
            vT[(h*5+3)*NPIX + pix] = (_Float16)a3;
            vT[(h*5+4)*NPIX + pix] = (_Float16)1.0f;
        } else {
            half4 hi = { (_Float16)a0, (_Float16)a1, (_Float16)a2, (_Float16)a3 };
            half4 lo = { (_Float16)(a0 - (float)hi[0]),
                         (_Float16)(a1 - (float)hi[1]),
                         (_Float16)(a2 - (float)hi[2]),
                         (_Float16)(a3 - (float)hi[3]) };
            half4* dhi = (m == 0) ? qhi : khi;
            half4* dlo = (m == 0) ? qlo : klo;
            dhi[h*NPIX + pix] = hi;
            dlo[h*NPIX + pix] = lo;
        }
    }
}

// ---------------------------------------------------------------------------
// Kernel 2a: MFMA local attention (split-K partials), scalar-addressed.
// grid = 16(hg) x 96 blocks of 4 waves; wave = (qt sub, seg).
// Per 16-key tile: S^T = Kh*Qh + Kh*Ql + Kl*Qh (mfma_f32_16x16x16_f16,
// d=4 zero-padded).  Q-fragment zeros at k>=4 make garbage K lanes harmless,
// so ALL lanes load K at (lane&15) — broadcast, no masking.  V B-fragment:
// plane min(c,4) of the 5-plane vT (col 4 = ones = ssum; cols>4 read the
// ones plane, landing in O columns that are never stored).
// ---------------------------------------------------------------------------
__global__ __launch_bounds__(256) void attn_mfma_kernel(
    const half4* __restrict__ qhi, const half4* __restrict__ qlo,
    const half4* __restrict__ khi, const half4* __restrict__ klo,
    const _Float16* __restrict__ vT,
    float* __restrict__ partA,     // [SSEG][16hg][3072 q][4]
    float* __restrict__ partS)     // [SSEG][16hg][3072 q]
{
    const int hg  = blockIdx.x / 96;
    const int h   = hg >> 1, g = hg & 1;
    const int wav = __builtin_amdgcn_readfirstlane(threadIdx.x >> 6);
    const int qt  = (blockIdx.x % 96) * 2 + (wav & 1);
    const int seg = wav >> 1;
    const int lane = threadIdx.x & 63;
    const int c   = lane & 15;
    const int g16 = lane >> 4;
    const int c0  = g * 16;

    // Q fragment (B operand): lanes g16==0 hold the 4 dims of query qt*16+c
    half4 qh = {}, ql = {};
    if (g16 == 0) {
        const int q   = qt * 16 + c;
        const int qy  = q / 24;
        const int pix = qy * W_IMG + g * 24 + (q - qy * 24);
        qh = qhi[h * NPIX + pix];
        ql = qlo[h * NPIX + pix];
    }

    const half4* khb = khi + h * NPIX;           // + koff (scalar) + c (lane)
    const half4* klb = klo + h * NPIX;
    const int vplane = (c < 4) ? c : 4;
    const _Float16* vb = vT + (h * 5 + vplane) * NPIX + 4 * g16;  // + koff

    f32x4 o = {0.f, 0.f, 0.f, 0.f};

    const int r0 = seg * (H_IMG / SSEG);
    #pragma unroll 2
    for (int r = 0; r < H_IMG / SSEG; ++r) {
        const int koff = (r0 + r) * W_IMG + c0;   // scalar

        const half4 kh0 = khb[koff + c];
        const half4 kl0 = klb[koff + c];
        const half4 kh1 = khb[koff + 16 + c];
        const half4 kl1 = klb[koff + 16 + c];
        const half4 vh0 = *reinterpret_cast<const half4*>(vb + koff);
        const half4 vh1 = *reinterpret_cast<const half4*>(vb + koff + 16);

        f32x4 s0 = {0.f, 0.f, 0.f, 0.f};
        f32x4 s1 = {0.f, 0.f, 0.f, 0.f};
        s0 = __builtin_amdgcn_mfma_f32_16x16x16f16(kl0, qh, s0, 0, 0, 0);
        s1 = __builtin_amdgcn_mfma_f32_16x16x16f16(kl1, qh, s1, 0, 0, 0);
        s0 = __builtin_amdgcn_mfma_f32_16x16x16f16(kh0, ql, s0, 0, 0, 0);
        s1 = __builtin_amdgcn_mfma_f32_16x16x16f16(kh1, ql, s1, 0, 0, 0);
        s0 = __builtin_amdgcn_mfma_f32_16x16x16f16(kh0, qh, s0, 0, 0, 0);
        s1 = __builtin_amdgcn_mfma_f32_16x16x16f16(kh1, qh, s1, 0, 0, 0);

        const half4 p0 = exp_pack(s0);
        const half4 p1 = exp_pack(s1);

        o = __builtin_amdgcn_mfma_f32_16x16x16f16(p0, vh0, o, 0, 0, 0);
        o = __builtin_amdgcn_mfma_f32_16x16x16f16(p1, vh1, o, 0, 0, 0);
    }

    // O fragment: lane holds O[q = qt*16 + 4*g16 + r][col c]; col 4 = ssum
    const int qb = (seg * 16 + hg) * 3072 + qt * 16 + g16 * 4;
    if (c < 4) {
        #pragma unroll
        for (int r = 0; r < 4; ++r) partA[(qb + r) * 4 + c] = o[r];
    } else if (c == 4) {
        #pragma unroll
        for (int r = 0; r < 4; ++r) partS[qb + r] = o[r];
    }
}

// ---------------------------------------------------------------------------
// Kernel 2b: combine split-K partials, normalize, write att[y][x][32].
// ---------------------------------------------------------------------------
__global__ __launch_bounds__(256) void attn_reduce_kernel(
    const f32x4* __restrict__ partA4,
    const float* __restrict__ partS,
    float* __restrict__ att)
{
    const int idx = blockIdx.x * 256 + threadIdx.x;  // 0..49151
    const int hg  = idx / 3072;
    const int q   = idx % 3072;
    const int h   = hg >> 1, g = hg & 1;

    f32x4 a = {0.f, 0.f, 0.f, 0.f};
    float ss = 0.f;
    #pragma unroll
    for (int s = 0; s < SSEG; ++s) {
        a  += partA4[(s * 16 + hg) * 3072 + q];
        ss += partS [(s * 16 + hg) * 3072 + q];
    }
    const float inv = 1.0f / ss;
    const int qy = q / 24;
    const int pix = qy * W_IMG + g * 24 + (q - qy * 24);
    *reinterpret_cast<float4*>(att + pix * DM + h * 4) =
        make_float4(a[0] * inv, a[1] * inv, a[2] * inv, a[3] * inv);
}

// ---------------------------------------------------------------------------
// Kernel 3: output 3x3 SAME conv (32 -> 64 ch, no bias).
// ---------------------------------------------------------------------------
__global__ __launch_bounds__(256) void out_conv_kernel(
    const float* __restrict__ att,
    const float* __restrict__ wo,
    float* __restrict__ out)
{
    const int cg  = blockIdx.x / 24;                 // uniform, 0..7
    const int pix = (blockIdx.x % 24) * 256 + threadIdx.x;
    const int y   = pix / W_IMG;
    const int x0  = pix % W_IMG;

    float acc[8];
    #pragma unroll
    for (int j = 0; j < 8; ++j) acc[j] = 0.f;

    for (int dy = -1; dy <= 1; ++dy) {
        const int yy = y + dy;
        if (yy < 0 || yy >= H_IMG) continue;
        for (int dx = -1; dx <= 1; ++dx) {
            const int xc = x0 + dx;
            if (xc < 0 || xc >= W_IMG) continue;
            const float* ap = att + (yy * W_IMG + xc) * DM;
            const float* wp = wo + ((dy + 1) * 3 + (dx + 1)) * DM * 64 + cg * 8;
            for (int ci = 0; ci < DM; ci += 4) {
                const float4 xv = *reinterpret_cast<const float4*>(ap + ci);
                #pragma unroll
                for (int j = 0; j < 8; ++j) {
                    acc[j] += xv.x * wp[(ci + 0) * 64 + j];
                    acc[j] += xv.y * wp[(ci + 1) * 64 + j];
                    acc[j] += xv.z * wp[(ci + 2) * 64 + j];
                    acc[j] += xv.w * wp[(ci + 3) * 64 + j];
                }
            }
        }
    }

    float* op = out + (y * W_IMG + x0) * 64 + cg * 8;
    *reinterpret_cast<float4*>(op + 0) = make_float4(acc[0], acc[1], acc[2], acc[3]);
    *reinterpret_cast<float4*>(op + 4) = make_float4(acc[4], acc[5], acc[6], acc[7]);
}

// ---------------------------------------------------------------------------
extern "C" void kernel_launch(void* const* d_in, const int* in_sizes, int n_in,
                              void* d_out, int out_size, void* d_ws, size_t ws_size,
                              hipStream_t stream)
{
    const float* x  = (const float*)d_in[0];
    const float* wq = (const float*)d_in[1];
    const float* bq = (const float*)d_in[2];
    const float* wk = (const float*)d_in[3];
    const float* bk = (const float*)d_in[4];
    const float* wv = (const float*)d_in[5];
    const float* bv = (const float*)d_in[6];
    const float* wo = (const float*)d_in[7];
    float* out = (float*)d_out;

    // workspace layout (bytes), all offsets 16B-aligned
    char* base = (char*)d_ws;
    half4*    qhi   = (half4*)(base + 0);          //  393216 B
    half4*    qlo   = (half4*)(base + 393216);
    half4*    khi   = (half4*)(base + 786432);
    half4*    klo   = (half4*)(base + 1179648);
    _Float16* vT    = (_Float16*)(base + 1572864); //  491520 B (8h x 5 planes)
    float*    partA = (float*)(base + 2064384);    // 1572864 B
    float*    partS = (float*)(base + 3637248);    //  393216 B
    float*    att   = (float*)(base + 4030464);    //  786432 B

    hipLaunchKernelGGL(qkv_conv_kernel, dim3(288), dim3(256), 0, stream,
                       x, wq, bq, wk, bk, wv, bv, qhi, qlo, khi, klo, vT);

    hipLaunchKernelGGL(attn_mfma_kernel, dim3(16 * 96), dim3(256), 0, stream,
                       qhi, qlo, khi, klo, vT, partA, partS);

    hipLaunchKernelGGL(attn_reduce_kernel, dim3(192), dim3(256), 0, stream,
                       (const f32x4*)partA, partS, att);

    hipLaunchKernelGGL(out_conv_kernel, dim3(192), dim3(256), 0, stream,
                       att, wo, out);
}

// Round 7
// 114.875 us; speedup vs baseline: 1.2482x; 1.1836x over previous
//
#include <hip/hip_runtime.h>

#define H_IMG 128
#define W_IMG 48
#define CIN   64
#define DM    32
#define NH    8
#define NPIX  6144
#define SSEG  4

// 0.5 (dh^-0.5) * log2(e): fold exp->exp2 conversion into q at conv time
#define Q_SCALE 0.7213475204444817f

typedef _Float16 half4 __attribute__((ext_vector_type(4)));
typedef __fp16   fp16x2 __attribute__((ext_vector_type(2)));
typedef float    f32x4 __attribute__((ext_vector_type(4)));

__device__ __forceinline__ float fexp2(float x) { return __builtin_amdgcn_exp2f(x); }

// exp2 the 4 logits of an S^T fragment and pack to f16 (RTZ; consistent in
// numerator and denominator so the bias cancels in the softmax ratio)
__device__ __forceinline__ half4 exp_pack(f32x4 s) {
    fp16x2 lo = __builtin_amdgcn_cvt_pkrtz(fexp2(s[0]), fexp2(s[1]));
    fp16x2 hi = __builtin_amdgcn_cvt_pkrtz(fexp2(s[2]), fexp2(s[3]));
    half4 p;
    p[0] = (_Float16)lo[0]; p[1] = (_Float16)lo[1];
    p[2] = (_Float16)hi[0]; p[3] = (_Float16)hi[1];
    return p;
}

// ---------------------------------------------------------------------------
// Kernel 1: fused QKV 3x3 SAME conv (3m x 4cg x 24, 256 thr, 2 heads/thread).
// Emits f16 hi/lo q,k (half4 per head-pixel) and 5-plane dim-major f16 V:
// vT[h*5 + d][pix] for d=0..3, plane d=4 = all ones (softmax denominator
// column for the PV mfma).
// ---------------------------------------------------------------------------
__global__ __launch_bounds__(256) void qkv_conv_kernel(
    const float* __restrict__ x,
    const float* __restrict__ wq, const float* __restrict__ bq,
    const float* __restrict__ wk, const float* __restrict__ bk,
    const float* __restrict__ wv, const float* __restrict__ bv,
    half4* __restrict__ qhi, half4* __restrict__ qlo,
    half4* __restrict__ khi, half4* __restrict__ klo,
    _Float16* __restrict__ vT)
{
    const int m   = blockIdx.x / 96;                 // 0=q 1=k 2=v (uniform)
    const int cg  = (blockIdx.x % 96) / 24;          // channel group (uniform)
    const int pix = (blockIdx.x % 24) * 256 + threadIdx.x;
    const int y   = pix / W_IMG;
    const int x0  = pix % W_IMG;

    const float* w = (m == 0) ? wq : (m == 1) ? wk : wv;
    const float* b = (m == 0) ? bq : (m == 1) ? bk : bv;

    float acc[8];
    #pragma unroll
    for (int j = 0; j < 8; ++j) acc[j] = b[cg * 8 + j];

    for (int dy = -1; dy <= 1; ++dy) {
        const int yy = y + dy;
        if (yy < 0 || yy >= H_IMG) continue;
        for (int dx = -1; dx <= 1; ++dx) {
            const int xc = x0 + dx;
            if (xc < 0 || xc >= W_IMG) continue;
            const float* xp = x + (yy * W_IMG + xc) * CIN;
            const float* wp = w + ((dy + 1) * 3 + (dx + 1)) * CIN * DM + cg * 8;
            for (int ci = 0; ci < CIN; ci += 4) {
                const float4 xv = *reinterpret_cast<const float4*>(xp + ci);
                #pragma unroll
                for (int j = 0; j < 8; ++j) {
                    acc[j] += xv.x * wp[(ci + 0) * DM + j];
                    acc[j] += xv.y * wp[(ci + 1) * DM + j];
                    acc[j] += xv.z * wp[(ci + 2) * DM + j];
                    acc[j] += xv.w * wp[(ci + 3) * DM + j];
                }
            }
        }
    }

    const float s = (m == 0) ? Q_SCALE : 1.0f;

    #pragma unroll
    for (int hh = 0; hh < 2; ++hh) {
        const int h = cg * 2 + hh;
        float a0 = acc[hh*4+0]*s, a1 = acc[hh*4+1]*s,
              a2 = acc[hh*4+2]*s, a3 = acc[hh*4+3]*s;
        if (m == 2) {
            vT[(h*5+0)*NPIX + pix] = (_Float16)a0;
            vT[(h*5+1)*NPIX + pix] = (_Float16)a1;
            vT[(h*5+2)*NPIX + pix] = (_Float16)a2;
            vT[(h*5+3)*NPIX + pix] = (_Float16)a3;
            vT[(h*5+4)*NPIX + pix] = (_Float16)1.0f;
        } else {
            half4 hi = { (_Float16)a0, (_Float16)a1, (_Float16)a2, (_Float16)a3 };
            half4 lo = { (_Float16)(a0 - (float)hi[0]),
                         (_Float16)(a1 - (float)hi[1]),
                         (_Float16)(a2 - (float)hi[2]),
                         (_Float16)(a3 - (float)hi[3]) };
            half4* dhi = (m == 0) ? qhi : khi;
            half4* dlo = (m == 0) ? qlo : klo;
            dhi[h*NPIX + pix] = hi;
            dlo[h*NPIX + pix] = lo;
        }
    }
}

// ---------------------------------------------------------------------------
// Kernel 2a: MFMA local attention (split-K partials), fused hi/lo QK.
// grid = 16(hg) x 192(qt) blocks of 4 waves; wave = one 32-row key segment.
// ONE mfma computes kh*qh + kh*ql + kl*qh via k-slot packing:
//   A rows (K):  slots0-3 = kh, 4-7 = kh, 8-11 = kl, 12-15 = dontcare
//   B cols (Q):  slots0-3 = qh, 4-7 = ql, 8-11 = qh, 12-15 = 0
// (per-lane operand selects by g16, hoisted out of the loop).
// exp2 -> f16 P fragment IS the A fragment of the PV mfma.  V B-fragment:
// plane min(c,4) of 5-plane vT (col 4 = ones = ssum; cols>4 harmless).
// Two independent O accumulators (tile parity) halve the serial chain.
// ---------------------------------------------------------------------------
__global__ __launch_bounds__(256) void attn_mfma_kernel(
    const half4* __restrict__ qhi, const half4* __restrict__ qlo,
    const half4* __restrict__ khi, const half4* __restrict__ klo,
    const _Float16* __restrict__ vT,
    float* __restrict__ partA,     // [SSEG][16hg][3072 q][4]
    float* __restrict__ partS)     // [SSEG][16hg][3072 q]
{
    const int qt  = blockIdx.x % 192;
    const int hg  = blockIdx.x / 192;
    const int h   = hg >> 1, g = hg & 1;
    const int seg = __builtin_amdgcn_readfirstlane(threadIdx.x >> 6);
    const int lane = threadIdx.x & 63;
    const int c   = lane & 15;
    const int g16 = lane >> 4;
    const int c0  = g * 16;

    // Q fragment (B operand): k-slots by g16: {qh, ql, qh, 0}
    half4 qf = {};
    {
        const int q   = qt * 16 + c;
        const int qy  = q / 24;
        const int pix = qy * W_IMG + g * 24 + (q - qy * 24);
        const half4* qsrc = (g16 == 1) ? qlo : qhi;
        if (g16 < 3) qf = qsrc[h * NPIX + pix];
    }

    // K fragment base (A operand): k-slots by g16: {kh, kh, kl, dontcare}
    const half4* kb = ((g16 == 2) ? klo : khi) + h * NPIX + c;

    // V fragment base (B operand): plane min(c,4); col 4 = ones (ssum)
    const int vplane = (c < 4) ? c : 4;
    const _Float16* vb = vT + (h * 5 + vplane) * NPIX + 4 * g16;

    const f32x4 zc = {0.f, 0.f, 0.f, 0.f};
    f32x4 oa = zc, ob = zc;

    const int r0 = seg * (H_IMG / SSEG);
    #pragma unroll 4
    for (int r = 0; r < H_IMG / SSEG; ++r) {
        const int koff = (r0 + r) * W_IMG + c0;   // scalar

        const half4 k0 = kb[koff];
        const half4 k1 = kb[koff + 16];
        const half4 v0 = *reinterpret_cast<const half4*>(vb + koff);
        const half4 v1 = *reinterpret_cast<const half4*>(vb + koff + 16);

        const f32x4 s0 = __builtin_amdgcn_mfma_f32_16x16x16f16(k0, qf, zc, 0, 0, 0);
        const f32x4 s1 = __builtin_amdgcn_mfma_f32_16x16x16f16(k1, qf, zc, 0, 0, 0);

        const half4 p0 = exp_pack(s0);
        const half4 p1 = exp_pack(s1);

        oa = __builtin_amdgcn_mfma_f32_16x16x16f16(p0, v0, oa, 0, 0, 0);
        ob = __builtin_amdgcn_mfma_f32_16x16x16f16(p1, v1, ob, 0, 0, 0);
    }

    const f32x4 o = oa + ob;

    // O fragment: lane holds O[q = qt*16 + 4*g16 + r][col c]; col 4 = ssum
    const int qb = (seg * 16 + hg) * 3072 + qt * 16 + g16 * 4;
    if (c < 4) {
        #pragma unroll
        for (int r = 0; r < 4; ++r) partA[(qb + r) * 4 + c] = o[r];
    } else if (c == 4) {
        #pragma unroll
        for (int r = 0; r < 4; ++r) partS[qb + r] = o[r];
    }
}

// ---------------------------------------------------------------------------
// Kernel 2b: combine split-K partials, normalize, write att[y][x][32].
// ---------------------------------------------------------------------------
__global__ __launch_bounds__(256) void attn_reduce_kernel(
    const f32x4* __restrict__ partA4,
    const float* __restrict__ partS,
    float* __restrict__ att)
{
    const int idx = blockIdx.x * 256 + threadIdx.x;  // 0..49151
    const int hg  = idx / 3072;
    const int q   = idx % 3072;
    const int h   = hg >> 1, g = hg & 1;

    f32x4 a = {0.f, 0.f, 0.f, 0.f};
    float ss = 0.f;
    #pragma unroll
    for (int s = 0; s < SSEG; ++s) {
        a  += partA4[(s * 16 + hg) * 3072 + q];
        ss += partS [(s * 16 + hg) * 3072 + q];
    }
    const float inv = 1.0f / ss;
    const int qy = q / 24;
    const int pix = qy * W_IMG + g * 24 + (q - qy * 24);
    *reinterpret_cast<float4*>(att + pix * DM + h * 4) =
        make_float4(a[0] * inv, a[1] * inv, a[2] * inv, a[3] * inv);
}

// ---------------------------------------------------------------------------
// Kernel 3: output 3x3 SAME conv (32 -> 64 ch, no bias).
// ---------------------------------------------------------------------------
__global__ __launch_bounds__(256) void out_conv_kernel(
    const float* __restrict__ att,
    const float* __restrict__ wo,
    float* __restrict__ out)
{
    const int cg  = blockIdx.x / 24;                 // uniform, 0..7
    const int pix = (blockIdx.x % 24) * 256 + threadIdx.x;
    const int y   = pix / W_IMG;
    const int x0  = pix % W_IMG;

    float acc[8];
    #pragma unroll
    for (int j = 0; j < 8; ++j) acc[j] = 0.f;

    for (int dy = -1; dy <= 1; ++dy) {
        const int yy = y + dy;
        if (yy < 0 || yy >= H_IMG) continue;
        for (int dx = -1; dx <= 1; ++dx) {
            const int xc = x0 + dx;
            if (xc < 0 || xc >= W_IMG) continue;
            const float* ap = att + (yy * W_IMG + xc) * DM;
            const float* wp = wo + ((dy + 1) * 3 + (dx + 1)) * DM * 64 + cg * 8;
            for (int ci = 0; ci < DM; ci += 4) {
                const float4 xv = *reinterpret_cast<const float4*>(ap + ci);
                #pragma unroll
                for (int j = 0; j < 8; ++j) {
                    acc[j] += xv.x * wp[(ci + 0) * 64 + j];
                    acc[j] += xv.y * wp[(ci + 1) * 64 + j];
                    acc[j] += xv.z * wp[(ci + 2) * 64 + j];
                    acc[j] += xv.w * wp[(ci + 3) * 64 + j];
                }
            }
        }
    }

    float* op = out + (y * W_IMG + x0) * 64 + cg * 8;
    *reinterpret_cast<float4*>(op + 0) = make_float4(acc[0], acc[1], acc[2], acc[3]);
    *reinterpret_cast<float4*>(op + 4) = make_float4(acc[4], acc[5], acc[6], acc[7]);
}

// ---------------------------------------------------------------------------
extern "C" void kernel_launch(void* const* d_in, const int* in_sizes, int n_in,
                              void* d_out, int out_size, void* d_ws, size_t ws_size,
                              hipStream_t stream)
{
    const float* x  = (const float*)d_in[0];
    const float* wq = (const float*)d_in[1];
    const float* bq = (const float*)d_in[2];
    const float* wk = (const float*)d_in[3];
    const float* bk = (const float*)d_in[4];
    const float* wv = (const float*)d_in[5];
    const float* bv = (const float*)d_in[6];
    const float* wo = (const float*)d_in[7];
    float* out = (float*)d_out;

    // workspace layout (bytes), all offsets 16B-aligned
    char* base = (char*)d_ws;
    half4*    qhi   = (half4*)(base + 0);          //  393216 B
    half4*    qlo   = (half4*)(base + 393216);
    half4*    khi   = (half4*)(base + 786432);
    half4*    klo   = (half4*)(base + 1179648);
    _Float16* vT    = (_Float16*)(base + 1572864); //  491520 B (8h x 5 planes)
    float*    partA = (float*)(base + 2064384);    // 3145728 B (SSEG=4)
    float*    partS = (float*)(base + 5210112);    //  786432 B
    float*    att   = (float*)(base + 5996544);    //  786432 B -> ends 6782976

    hipLaunchKernelGGL(qkv_conv_kernel, dim3(288), dim3(256), 0, stream,
                       x, wq, bq, wk, bk, wv, bv, qhi, qlo, khi, klo, vT);

    hipLaunchKernelGGL(attn_mfma_kernel, dim3(16 * 192), dim3(256), 0, stream,
                       qhi, qlo, khi, klo, vT, partA, partS);

    hipLaunchKernelGGL(attn_reduce_kernel, dim3(192), dim3(256), 0, stream,
                       (const f32x4*)partA, partS, att);

    hipLaunchKernelGGL(out_conv_kernel, dim3(192), dim3(256), 0, stream,
                       att, wo, out);
}

// Round 8
// 87.052 us; speedup vs baseline: 1.6471x; 1.3196x over previous
//
#include <hip/hip_runtime.h>

#define H_IMG 128
#define W_IMG 48
#define CIN   64
#define DM    32
#define NH    8
#define NPIX  6144
#define SSEG  4

// 0.5 (dh^-0.5) * log2(e): fold exp->exp2 conversion into q at conv time
#define Q_SCALE 0.7213475204444817f

typedef _Float16 half4 __attribute__((ext_vector_type(4)));
typedef __fp16   fp16x2 __attribute__((ext_vector_type(2)));
typedef float    f32x4 __attribute__((ext_vector_type(4)));

__device__ __forceinline__ float fexp2(float x) { return __builtin_amdgcn_exp2f(x); }

// exp2 the 4 logits of an S^T fragment and pack to f16 (RTZ; consistent in
// numerator and denominator so the bias cancels in the softmax ratio)
__device__ __forceinline__ half4 exp_pack(f32x4 s) {
    fp16x2 lo = __builtin_amdgcn_cvt_pkrtz(fexp2(s[0]), fexp2(s[1]));
    fp16x2 hi = __builtin_amdgcn_cvt_pkrtz(fexp2(s[2]), fexp2(s[3]));
    half4 p;
    p[0] = (_Float16)lo[0]; p[1] = (_Float16)lo[1];
    p[2] = (_Float16)hi[0]; p[3] = (_Float16)hi[1];
    return p;
}

// ---------------------------------------------------------------------------
// Kernel 1: fused QKV 3x3 SAME conv (3m x 4cg x 24, 256 thr, 2 heads/thread).
// Emits f16 hi/lo q,k (half4 per head-pixel) and 5-plane dim-major f16 V:
// vT[h*5 + d][pix] for d=0..3, plane d=4 = all ones (softmax denominator
// column for the PV mfma).
// ---------------------------------------------------------------------------
__global__ __launch_bounds__(256) void qkv_conv_kernel(
    const float* __restrict__ x,
    const float* __restrict__ wq, const float* __restrict__ bq,
    const float* __restrict__ wk, const float* __restrict__ bk,
    const float* __restrict__ wv, const float* __restrict__ bv,
    half4* __restrict__ qhi, half4* __restrict__ qlo,
    half4* __restrict__ khi, half4* __restrict__ klo,
    _Float16* __restrict__ vT)
{
    const int m   = blockIdx.x / 96;                 // 0=q 1=k 2=v (uniform)
    const int cg  = (blockIdx.x % 96) / 24;          // channel group (uniform)
    const int pix = (blockIdx.x % 24) * 256 + threadIdx.x;
    const int y   = pix / W_IMG;
    const int x0  = pix % W_IMG;

    const float* w = (m == 0) ? wq : (m == 1) ? wk : wv;
    const float* b = (m == 0) ? bq : (m == 1) ? bk : bv;

    float acc[8];
    #pragma unroll
    for (int j = 0; j < 8; ++j) acc[j] = b[cg * 8 + j];

    for (int dy = -1; dy <= 1; ++dy) {
        const int yy = y + dy;
        if (yy < 0 || yy >= H_IMG) continue;
        for (int dx = -1; dx <= 1; ++dx) {
            const int xc = x0 + dx;
            if (xc < 0 || xc >= W_IMG) continue;
            const float* xp = x + (yy * W_IMG + xc) * CIN;
            const float* wp = w + ((dy + 1) * 3 + (dx + 1)) * CIN * DM + cg * 8;
            for (int ci = 0; ci < CIN; ci += 4) {
                const float4 xv = *reinterpret_cast<const float4*>(xp + ci);
                #pragma unroll
                for (int j = 0; j < 8; ++j) {
                    acc[j] += xv.x * wp[(ci + 0) * DM + j];
                    acc[j] += xv.y * wp[(ci + 1) * DM + j];
                    acc[j] += xv.z * wp[(ci + 2) * DM + j];
                    acc[j] += xv.w * wp[(ci + 3) * DM + j];
                }
            }
        }
    }

    const float s = (m == 0) ? Q_SCALE : 1.0f;

    #pragma unroll
    for (int hh = 0; hh < 2; ++hh) {
        const int h = cg * 2 + hh;
        float a0 = acc[hh*4+0]*s, a1 = acc[hh*4+1]*s,
              a2 = acc[hh*4+2]*s, a3 = acc[hh*4+3]*s;
        if (m == 2) {
            vT[(h*5+0)*NPIX + pix] = (_Float16)a0;
            vT[(h*5+1)*NPIX + pix] = (_Float16)a1;
            vT[(h*5+2)*NPIX + pix] = (_Float16)a2;
            vT[(h*5+3)*NPIX + pix] = (_Float16)a3;
            vT[(h*5+4)*NPIX + pix] = (_Float16)1.0f;
        } else {
            half4 hi = { (_Float16)a0, (_Float16)a1, (_Float16)a2, (_Float16)a3 };
            half4 lo = { (_Float16)(a0 - (float)hi[0]),
                         (_Float16)(a1 - (float)hi[1]),
                         (_Float16)(a2 - (float)hi[2]),
                         (_Float16)(a3 - (float)hi[3]) };
            half4* dhi = (m == 0) ? qhi : khi;
            half4* dlo = (m == 0) ? qlo : klo;
            dhi[h*NPIX + pix] = hi;
            dlo[h*NPIX + pix] = lo;
        }
    }
}

// ---------------------------------------------------------------------------
// Kernel 2a: MFMA local attention (split-K partials), fused hi/lo QK,
// TWO query tiles per wave (K/V loads amortized, 2x independent chains).
// grid = 16(hg) x 96; block = 4 waves, all same key segment (seg), each wave
// a different query-tile pair -> the 4 waves stream identical K/V addresses
// (L1 temporal sharing).  Per row: 4 loads, 4 QK mfma, 4 exp_pack, 4 PV mfma.
// Fused QK k-slot packing (per-lane selects by g16, hoisted):
//   A rows (K):  slots0-3 = kh, 4-7 = kh, 8-11 = kl, 12-15 = dontcare
//   B cols (Q):  slots0-3 = qh, 4-7 = ql, 8-11 = qh, 12-15 = 0
// V B-fragment: plane min(c,4) of 5-plane vT (col 4 = ones = ssum).
// ---------------------------------------------------------------------------
__global__ __launch_bounds__(256) void attn_mfma_kernel(
    const half4* __restrict__ qhi, const half4* __restrict__ qlo,
    const half4* __restrict__ khi, const half4* __restrict__ klo,
    const _Float16* __restrict__ vT,
    float* __restrict__ partA,     // [SSEG][16hg][3072 q][4]
    float* __restrict__ partS)     // [SSEG][16hg][3072 q]
{
    const int hg   = blockIdx.x / 96;
    const int rest = blockIdx.x % 96;
    const int seg  = __builtin_amdgcn_readfirstlane(rest / 24);
    const int qg   = rest % 24;
    const int wav  = __builtin_amdgcn_readfirstlane(threadIdx.x >> 6);
    const int qtA  = (qg * 4 + wav) * 2;      // tiles qtA, qtA+1
    const int h    = hg >> 1, g = hg & 1;
    const int lane = threadIdx.x & 63;
    const int c    = lane & 15;
    const int g16  = lane >> 4;
    const int c0   = g * 16;

    // Q fragments (B operand) for both tiles: k-slots by g16: {qh, ql, qh, 0}
    half4 qfA = {}, qfB = {};
    {
        const half4* qsrc = (g16 == 1) ? qlo : qhi;
        const int qa  = qtA * 16 + c;
        const int qay = qa / 24;
        const int qb  = qa + 16;
        const int qby = qb / 24;
        if (g16 < 3) {
            qfA = qsrc[h * NPIX + qay * W_IMG + g * 24 + (qa - qay * 24)];
            qfB = qsrc[h * NPIX + qby * W_IMG + g * 24 + (qb - qby * 24)];
        }
    }

    // K fragment base (A operand): k-slots by g16: {kh, kh, kl, dontcare}
    const half4* kb = ((g16 == 2) ? klo : khi) + h * NPIX + c;

    // V fragment base (B operand): plane min(c,4); col 4 = ones (ssum)
    const int vplane = (c < 4) ? c : 4;
    const _Float16* vb = vT + (h * 5 + vplane) * NPIX + 4 * g16;

    const f32x4 zc = {0.f, 0.f, 0.f, 0.f};
    f32x4 oA0 = zc, oA1 = zc, oB0 = zc, oB1 = zc;

    const int r0 = seg * (H_IMG / SSEG);
    #pragma unroll 4
    for (int r = 0; r < H_IMG / SSEG; ++r) {
        const int koff = (r0 + r) * W_IMG + c0;   // scalar

        const half4 k0 = kb[koff];
        const half4 k1 = kb[koff + 16];
        const half4 v0 = *reinterpret_cast<const half4*>(vb + koff);
        const half4 v1 = *reinterpret_cast<const half4*>(vb + koff + 16);

        const f32x4 sA0 = __builtin_amdgcn_mfma_f32_16x16x16f16(k0, qfA, zc, 0, 0, 0);
        const f32x4 sA1 = __builtin_amdgcn_mfma_f32_16x16x16f16(k1, qfA, zc, 0, 0, 0);
        const f32x4 sB0 = __builtin_amdgcn_mfma_f32_16x16x16f16(k0, qfB, zc, 0, 0, 0);
        const f32x4 sB1 = __builtin_amdgcn_mfma_f32_16x16x16f16(k1, qfB, zc, 0, 0, 0);

        const half4 pA0 = exp_pack(sA0);
        const half4 pA1 = exp_pack(sA1);
        const half4 pB0 = exp_pack(sB0);
        const half4 pB1 = exp_pack(sB1);

        oA0 = __builtin_amdgcn_mfma_f32_16x16x16f16(pA0, v0, oA0, 0, 0, 0);
        oA1 = __builtin_amdgcn_mfma_f32_16x16x16f16(pA1, v1, oA1, 0, 0, 0);
        oB0 = __builtin_amdgcn_mfma_f32_16x16x16f16(pB0, v0, oB0, 0, 0, 0);
        oB1 = __builtin_amdgcn_mfma_f32_16x16x16f16(pB1, v1, oB1, 0, 0, 0);
    }

    const f32x4 oA = oA0 + oA1;
    const f32x4 oB = oB0 + oB1;

    // O fragments: lane holds O[q = qt*16 + 4*g16 + r][col c]; col 4 = ssum
    const int base = (seg * 16 + hg) * 3072;
    const int qa = base + qtA * 16 + g16 * 4;
    const int qb = qa + 16;
    if (c < 4) {
        #pragma unroll
        for (int r = 0; r < 4; ++r) partA[(qa + r) * 4 + c] = oA[r];
        #pragma unroll
        for (int r = 0; r < 4; ++r) partA[(qb + r) * 4 + c] = oB[r];
    } else if (c == 4) {
        #pragma unroll
        for (int r = 0; r < 4; ++r) partS[qa + r] = oA[r];
        #pragma unroll
        for (int r = 0; r < 4; ++r) partS[qb + r] = oB[r];
    }
}

// ---------------------------------------------------------------------------
// Kernel 2b: combine split-K partials, normalize, write att[y][x][32].
// ---------------------------------------------------------------------------
__global__ __launch_bounds__(256) void attn_reduce_kernel(
    const f32x4* __restrict__ partA4,
    const float* __restrict__ partS,
    float* __restrict__ att)
{
    const int idx = blockIdx.x * 256 + threadIdx.x;  // 0..49151
    const int hg  = idx / 3072;
    const int q   = idx % 3072;
    const int h   = hg >> 1, g = hg & 1;

    f32x4 a = {0.f, 0.f, 0.f, 0.f};
    float ss = 0.f;
    #pragma unroll
    for (int s = 0; s < SSEG; ++s) {
        a  += partA4[(s * 16 + hg) * 3072 + q];
        ss += partS [(s * 16 + hg) * 3072 + q];
    }
    const float inv = 1.0f / ss;
    const int qy = q / 24;
    const int pix = qy * W_IMG + g * 24 + (q - qy * 24);
    *reinterpret_cast<float4*>(att + pix * DM + h * 4) =
        make_float4(a[0] * inv, a[1] * inv, a[2] * inv, a[3] * inv);
}

// ---------------------------------------------------------------------------
// Kernel 3: output 3x3 SAME conv (32 -> 64 ch, no bias).
// ---------------------------------------------------------------------------
__global__ __launch_bounds__(256) void out_conv_kernel(
    const float* __restrict__ att,
    const float* __restrict__ wo,
    float* __restrict__ out)
{
    const int cg  = blockIdx.x / 24;                 // uniform, 0..7
    const int pix = (blockIdx.x % 24) * 256 + threadIdx.x;
    const int y   = pix / W_IMG;
    const int x0  = pix % W_IMG;

    float acc[8];
    #pragma unroll
    for (int j = 0; j < 8; ++j) acc[j] = 0.f;

    for (int dy = -1; dy <= 1; ++dy) {
        const int yy = y + dy;
        if (yy < 0 || yy >= H_IMG) continue;
        for (int dx = -1; dx <= 1; ++dx) {
            const int xc = x0 + dx;
            if (xc < 0 || xc >= W_IMG) continue;
            const float* ap = att + (yy * W_IMG + xc) * DM;
            const float* wp = wo + ((dy + 1) * 3 + (dx + 1)) * DM * 64 + cg * 8;
            for (int ci = 0; ci < DM; ci += 4) {
                const float4 xv = *reinterpret_cast<const float4*>(ap + ci);
                #pragma unroll
                for (int j = 0; j < 8; ++j) {
                    acc[j] += xv.x * wp[(ci + 0) * 64 + j];
                    acc[j] += xv.y * wp[(ci + 1) * 64 + j];
                    acc[j] += xv.z * wp[(ci + 2) * 64 + j];
                    acc[j] += xv.w * wp[(ci + 3) * 64 + j];
                }
            }
        }
    }

    float* op = out + (y * W_IMG + x0) * 64 + cg * 8;
    *reinterpret_cast<float4*>(op + 0) = make_float4(acc[0], acc[1], acc[2], acc[3]);
    *reinterpret_cast<float4*>(op + 4) = make_float4(acc[4], acc[5], acc[6], acc[7]);
}

// ---------------------------------------------------------------------------
extern "C" void kernel_launch(void* const* d_in, const int* in_sizes, int n_in,
                              void* d_out, int out_size, void* d_ws, size_t ws_size,
                              hipStream_t stream)
{
    const float* x  = (const float*)d_in[0];
    const float* wq = (const float*)d_in[1];
    const float* bq = (const float*)d_in[2];
    const float* wk = (const float*)d_in[3];
    const float* bk = (const float*)d_in[4];
    const float* wv = (const float*)d_in[5];
    const float* bv = (const float*)d_in[6];
    const float* wo = (const float*)d_in[7];
    float* out = (float*)d_out;

    // workspace layout (bytes), all offsets 16B-aligned
    char* base = (char*)d_ws;
    half4*    qhi   = (half4*)(base + 0);          //  393216 B
    half4*    qlo   = (half4*)(base + 393216);
    half4*    khi   = (half4*)(base + 786432);
    half4*    klo   = (half4*)(base + 1179648);
    _Float16* vT    = (_Float16*)(base + 1572864); //  491520 B (8h x 5 planes)
    float*    partA = (float*)(base + 2064384);    // 3145728 B (SSEG=4)
    float*    partS = (float*)(base + 5210112);    //  786432 B
    float*    att   = (float*)(base + 5996544);    //  786432 B -> ends 6782976

    hipLaunchKernelGGL(qkv_conv_kernel, dim3(288), dim3(256), 0, stream,
                       x, wq, bq, wk, bk, wv, bv, qhi, qlo, khi, klo, vT);

    hipLaunchKernelGGL(attn_mfma_kernel, dim3(16 * 96), dim3(256), 0, stream,
                       qhi, qlo, khi, klo, vT, partA, partS);

    hipLaunchKernelGGL(attn_reduce_kernel, dim3(192), dim3(256), 0, stream,
                       (const f32x4*)partA, partS, att);

    hipLaunchKernelGGL(out_conv_kernel, dim3(192), dim3(256), 0, stream,
                       att, wo, out);
}